// Round 1
// baseline (139.186 us; speedup 1.0000x reference)
//
#include <hip/hip_runtime.h>
#include <hip/hip_bf16.h>

// SimCLR NT-Xent loss, fused bf16-MFMA flash-logsumexp.
// N=4096 rows (2B), D=512, tau=0.1. loss_i = lse_{j!=i}(sim_ij*10) - sim_{i, i^2048}*10
// out[0] = sum_i loss_i / 4096.

#define NROWS 4096
#define DDIM  512
#define INV_TAU 10.0f
#define NSPLIT 8                 // column splits
#define QCOLS (NROWS / NSPLIT)   // 512 cols per split
#define BM 64                    // rows per block (4 waves x 16)
#define NEG_INF (-3.0e38f)

typedef __bf16 bf16x8 __attribute__((ext_vector_type(8)));
typedef float  f32x4  __attribute__((ext_vector_type(4)));

// ---------------- kernel 0: fp32 -> bf16 ----------------
__global__ void jl_cvt(const float* __restrict__ in, __bf16* __restrict__ out) {
    int i = (blockIdx.x * 256 + threadIdx.x) * 8;
    float4 a = *(const float4*)(in + i);
    float4 b = *(const float4*)(in + i + 4);
    bf16x8 v;
    v[0] = (__bf16)a.x; v[1] = (__bf16)a.y; v[2] = (__bf16)a.z; v[3] = (__bf16)a.w;
    v[4] = (__bf16)b.x; v[5] = (__bf16)b.y; v[6] = (__bf16)b.z; v[7] = (__bf16)b.w;
    *(bf16x8*)(out + i) = v;
}

// ---------------- kernel 1: fused GEMM + online logsumexp partials ----------------
// grid = (NROWS/BM) * NSPLIT blocks, 256 threads (4 waves).
// block: rows [rb*BM, rb*BM+64), cols [q*QCOLS, q*QCOLS+512)
// wave w: rows [rb*BM + 16w, +16)
__global__ __launch_bounds__(256, 2) void jl_main(const __bf16* __restrict__ rb,
                                                  float* __restrict__ pm,
                                                  float* __restrict__ ps,
                                                  float* __restrict__ pos) {
    const int rbk  = blockIdx.x >> 3;   // row block 0..63
    const int q    = blockIdx.x & 7;    // col split 0..7
    const int wave = threadIdx.x >> 6;  // 0..3
    const int lane = threadIdx.x & 63;

    const int row0 = rbk * BM + wave * 16;  // wave's first row
    const int col0 = q * QCOLS;

    const int lrow = lane & 15;   // A row / B col / D col index
    const int lk   = lane >> 4;   // k sub-block 0..3

    // A fragments: A[i][k] at lane: i = lane&15, k = 8*(lane>>4)+e.  16 k-blocks cover K=512.
    bf16x8 afrag[16];
    {
        const __bf16* arow = rb + (size_t)(row0 + lrow) * DDIM + lk * 8;
        #pragma unroll
        for (int kb = 0; kb < 16; ++kb)
            afrag[kb] = *(const bf16x8*)(arow + kb * 32);
    }

    // lane-local online logsumexp state: rows 4*lk + r (r=0..3), column subset {lrow mod 16}
    float m[4], s[4];
    #pragma unroll
    for (int r = 0; r < 4; ++r) { m[r] = NEG_INF; s[r] = 0.0f; }

    for (int jt = 0; jt < QCOLS / 16; ++jt) {
        const __bf16* brow = rb + (size_t)(col0 + jt * 16 + lrow) * DDIM + lk * 8;
        f32x4 acc = {0.0f, 0.0f, 0.0f, 0.0f};
        #pragma unroll
        for (int kb = 0; kb < 16; ++kb) {
            bf16x8 bfrag = *(const bf16x8*)(brow + kb * 32);
            acc = __builtin_amdgcn_mfma_f32_16x16x32_bf16(afrag[kb], bfrag, acc, 0, 0, 0);
        }
        const int gcol = col0 + jt * 16 + lrow;   // D col = lane&15
        #pragma unroll
        for (int r = 0; r < 4; ++r) {
            const int grow = row0 + 4 * lk + r;   // D row = 4*(lane>>4)+reg
            float x = acc[r] * INV_TAU;
            if (gcol == (grow ^ 2048)) pos[grow] = x;  // positive logit (unique writer)
            if (gcol == grow) continue;                // exclude self
            if (x <= m[r]) {
                s[r] += __expf(x - m[r]);
            } else {
                s[r] = s[r] * __expf(m[r] - x) + 1.0f;
                m[r] = x;
            }
        }
    }

    // merge (m,s) across the 16 lanes of each row group, write partials
    #pragma unroll
    for (int r = 0; r < 4; ++r) {
        float mm = m[r], ss = s[r];
        #pragma unroll
        for (int off = 1; off < 16; off <<= 1) {
            float mo = __shfl_xor(mm, off, 64);
            float so = __shfl_xor(ss, off, 64);
            float mn = fmaxf(mm, mo);
            ss = ss * __expf(mm - mn) + so * __expf(mo - mn);
            mm = mn;
        }
        if (lrow == 0) {
            const int grow = row0 + 4 * lk + r;
            pm[grow * NSPLIT + q] = mm;
            ps[grow * NSPLIT + q] = ss;
        }
    }
}

// ---------------- kernel 2: merge partials -> scalar loss ----------------
__global__ void jl_merge(const float* __restrict__ pm, const float* __restrict__ ps,
                         const float* __restrict__ pos, float* __restrict__ out) {
    __shared__ float red[256];
    const int t = threadIdx.x;
    float acc = 0.0f;
    for (int i = t; i < NROWS; i += 256) {
        float mb = NEG_INF;
        #pragma unroll
        for (int qq = 0; qq < NSPLIT; ++qq) mb = fmaxf(mb, pm[i * NSPLIT + qq]);
        float st = 0.0f;
        #pragma unroll
        for (int qq = 0; qq < NSPLIT; ++qq)
            st += ps[i * NSPLIT + qq] * __expf(pm[i * NSPLIT + qq] - mb);
        acc += mb + __logf(st) - pos[i];
    }
    red[t] = acc;
    __syncthreads();
    for (int off = 128; off > 0; off >>= 1) {
        if (t < off) red[t] += red[t + off];
        __syncthreads();
    }
    if (t == 0) out[0] = red[0] * (1.0f / (float)NROWS);
}

extern "C" void kernel_launch(void* const* d_in, const int* in_sizes, int n_in,
                              void* d_out, int out_size, void* d_ws, size_t ws_size,
                              hipStream_t stream) {
    const float* rep = (const float*)d_in[0];
    float* out = (float*)d_out;

    // workspace layout
    __bf16* rbuf = (__bf16*)d_ws;                                  // 4 MB
    float*  pm   = (float*)((char*)d_ws + (size_t)NROWS * DDIM * 2);
    float*  ps   = pm + NROWS * NSPLIT;
    float*  pos  = ps + NROWS * NSPLIT;

    // 0: convert to bf16
    jl_cvt<<<(NROWS * DDIM) / (256 * 8), 256, 0, stream>>>(rep, rbuf);
    // 1: fused gemm + partial logsumexp
    jl_main<<<(NROWS / BM) * NSPLIT, 256, 0, stream>>>(rbuf, pm, ps, pos);
    // 2: merge to scalar
    jl_merge<<<1, 256, 0, stream>>>(pm, ps, pos, out);
}

// Round 2
// 63.291 us; speedup vs baseline: 2.1991x; 2.1991x over previous
//
#include <hip/hip_runtime.h>
#include <hip/hip_bf16.h>

// SimCLR NT-Xent loss, fused bf16-MFMA flash-logsumexp, v2:
// LDS-staged B (global_load_lds, fragment-ordered -> conflict-free ds_read),
// A resident in VGPRs, 4 independent MFMA chains, NSPLIT=16 for occupancy.

#define NROWS 4096
#define DDIM  512
#define INV_TAU 10.0f
#define NSPLIT 16                // column splits
#define QCOLS (NROWS / NSPLIT)   // 256 cols per split
#define NT (QCOLS / 16)          // 16 column tiles per block
#define BM 64                    // rows per block (4 waves x 16)
#define NEG_INF (-3.0e38f)

typedef __bf16 bf16x8 __attribute__((ext_vector_type(8)));
typedef float  f32x4  __attribute__((ext_vector_type(4)));

#define GLOAD_LDS16(g, l) __builtin_amdgcn_global_load_lds(                    \
    (const __attribute__((address_space(1))) void*)(g),                        \
    (__attribute__((address_space(3))) void*)(l), 16, 0, 0)

// ---------------- kernel 0: fp32 -> bf16 ----------------
__global__ void jl_cvt(const float* __restrict__ in, __bf16* __restrict__ out) {
    int i = (blockIdx.x * 256 + threadIdx.x) * 8;
    float4 a = *(const float4*)(in + i);
    float4 b = *(const float4*)(in + i + 4);
    bf16x8 v;
    v[0] = (__bf16)a.x; v[1] = (__bf16)a.y; v[2] = (__bf16)a.z; v[3] = (__bf16)a.w;
    v[4] = (__bf16)b.x; v[5] = (__bf16)b.y; v[6] = (__bf16)b.z; v[7] = (__bf16)b.w;
    *(bf16x8*)(out + i) = v;
}

// ---------------- kernel 1: fused GEMM + online logsumexp partials ----------------
// grid = (NROWS/BM) * NSPLIT blocks, 256 threads (4 waves).
// block: rows [rbk*64, +64), cols [q*256, +256). wave w: rows [rbk*64 + 16w, +16)
__global__ __launch_bounds__(256, 4) void jl_main(const __bf16* __restrict__ rb,
                                                  float* __restrict__ pm,
                                                  float* __restrict__ ps,
                                                  float* __restrict__ pos) {
    // LDS: double-buffered B tile in MFMA-fragment order: smem[buf][kb][lane] = 16B
    __shared__ bf16x8 smem[2][16][64];

    const int rbk  = blockIdx.x >> 4;   // row block 0..63
    const int q    = blockIdx.x & 15;   // col split 0..15
    const int wave = threadIdx.x >> 6;  // 0..3
    const int lane = threadIdx.x & 63;

    const int row0 = rbk * BM + wave * 16;
    const int col0 = q * QCOLS;

    const int lrow = lane & 15;   // A row / B col / D col index
    const int lk   = lane >> 4;   // k sub-block 0..3

    // A fragments, resident: A[row0+lrow][kb*32 + lk*8 + e], 16 kb-blocks = K 512.
    bf16x8 afrag[16];
    {
        const __bf16* arow = rb + (size_t)(row0 + lrow) * DDIM + lk * 8;
        #pragma unroll
        for (int kb = 0; kb < 16; ++kb)
            afrag[kb] = *(const bf16x8*)(arow + kb * 32);
    }

    // per-lane fragment-ordered global source for B staging:
    // lane -> (col = lane&15, koff = (lane>>4)*8); wave w stages kb = 4w..4w+3.
    const __bf16* gB = rb + (size_t)(col0 + lrow) * DDIM + lk * 8;

    // prologue: stage tile 0 into buf 0
    #pragma unroll
    for (int i = 0; i < 4; ++i) {
        int kb = wave * 4 + i;
        GLOAD_LDS16(gB + kb * 32, &smem[0][kb][0]);
    }
    __syncthreads();

    float m[4], s[4];
    #pragma unroll
    for (int r = 0; r < 4; ++r) { m[r] = NEG_INF; s[r] = 0.0f; }

    int cur = 0;
    for (int jt = 0; jt < NT; ++jt) {
        // stage next tile into the other buffer
        if (jt + 1 < NT) {
            const __bf16* gN = gB + (size_t)(jt + 1) * 16 * DDIM;
            #pragma unroll
            for (int i = 0; i < 4; ++i) {
                int kb = wave * 4 + i;
                GLOAD_LDS16(gN + kb * 32, &smem[cur ^ 1][kb][0]);
            }
        }

        // compute on current buffer: 4 independent MFMA chains of depth 4
        f32x4 acc[4];
        #pragma unroll
        for (int c = 0; c < 4; ++c) acc[c] = (f32x4){0.f, 0.f, 0.f, 0.f};
        #pragma unroll
        for (int kb = 0; kb < 16; ++kb) {
            bf16x8 b = smem[cur][kb][lane];
            acc[kb & 3] = __builtin_amdgcn_mfma_f32_16x16x32_bf16(afrag[kb], b, acc[kb & 3], 0, 0, 0);
        }
        f32x4 accs = (acc[0] + acc[1]) + (acc[2] + acc[3]);

        // online logsumexp epilogue (branchless diagonal mask)
        const int gcol = col0 + jt * 16 + lrow;
        #pragma unroll
        for (int r = 0; r < 4; ++r) {
            const int grow = row0 + 4 * lk + r;
            float x = accs[r] * INV_TAU;
            if (gcol == (grow ^ 2048)) pos[grow] = x;     // positive logit (unique writer)
            if (gcol == grow) x = -INFINITY;              // exclude self
            float mn = fmaxf(m[r], x);
            s[r] = s[r] * __expf(m[r] - mn) + __expf(x - mn);
            m[r] = mn;
        }

        __syncthreads();   // drains vmcnt (next tile staged) + all waves done with cur
        cur ^= 1;
    }

    // merge (m,s) across the 16 lanes of each row group, write partials
    #pragma unroll
    for (int r = 0; r < 4; ++r) {
        float mm = m[r], ss = s[r];
        #pragma unroll
        for (int off = 1; off < 16; off <<= 1) {
            float mo = __shfl_xor(mm, off, 64);
            float so = __shfl_xor(ss, off, 64);
            float mn = fmaxf(mm, mo);
            ss = ss * __expf(mm - mn) + so * __expf(mo - mn);
            mm = mn;
        }
        if (lrow == 0) {
            const int grow = row0 + 4 * lk + r;
            pm[grow * NSPLIT + q] = mm;
            ps[grow * NSPLIT + q] = ss;
        }
    }
}

// ---------------- kernel 2: merge partials -> scalar loss ----------------
__global__ void jl_merge(const float* __restrict__ pm, const float* __restrict__ ps,
                         const float* __restrict__ pos, float* __restrict__ out) {
    __shared__ float red[256];
    const int t = threadIdx.x;
    float acc = 0.0f;
    for (int i = t; i < NROWS; i += 256) {
        float mb = NEG_INF;
        #pragma unroll
        for (int qq = 0; qq < NSPLIT; ++qq) mb = fmaxf(mb, pm[i * NSPLIT + qq]);
        float st = 0.0f;
        #pragma unroll
        for (int qq = 0; qq < NSPLIT; ++qq)
            st += ps[i * NSPLIT + qq] * __expf(pm[i * NSPLIT + qq] - mb);
        acc += mb + __logf(st) - pos[i];
    }
    red[t] = acc;
    __syncthreads();
    for (int off = 128; off > 0; off >>= 1) {
        if (t < off) red[t] += red[t + off];
        __syncthreads();
    }
    if (t == 0) out[0] = red[0] * (1.0f / (float)NROWS);
}

extern "C" void kernel_launch(void* const* d_in, const int* in_sizes, int n_in,
                              void* d_out, int out_size, void* d_ws, size_t ws_size,
                              hipStream_t stream) {
    const float* rep = (const float*)d_in[0];
    float* out = (float*)d_out;

    // workspace layout
    __bf16* rbuf = (__bf16*)d_ws;                                  // 4 MB
    float*  pm   = (float*)((char*)d_ws + (size_t)NROWS * DDIM * 2);
    float*  ps   = pm + NROWS * NSPLIT;
    float*  pos  = ps + NROWS * NSPLIT;

    jl_cvt<<<(NROWS * DDIM) / (256 * 8), 256, 0, stream>>>(rep, rbuf);
    jl_main<<<(NROWS / BM) * NSPLIT, 256, 0, stream>>>(rbuf, pm, ps, pos);
    jl_merge<<<1, 256, 0, stream>>>(pm, ps, pos, out);
}

// Round 3
// 62.327 us; speedup vs baseline: 2.2332x; 1.0155x over previous
//
#include <hip/hip_runtime.h>
#include <hip/hip_bf16.h>

// SimCLR NT-Xent loss v3: pinned-resident A (asm), log2-prescaled A, defer-max
// epilogue, uniform-branch pos/diag, LDS-staged B via global_load_lds.

#define NROWS 4096
#define DDIM  512
#define NSPLIT 16                // column splits
#define QCOLS (NROWS / NSPLIT)   // 256 cols per split
#define NT (QCOLS / 16)          // 16 column tiles per block
#define BM 64                    // rows per block (4 waves x 16)
#define NEG_BIG (-3.0e38f)
#define CSCALE 14.4269504088896340736f   // 10 * log2(e): logits in log2 units
#define LN2 0.69314718055994530942f
#define THR 40.0f                // defer-max threshold (log2 units)

typedef __bf16 bf16x8 __attribute__((ext_vector_type(8)));
typedef float  f32x4  __attribute__((ext_vector_type(4)));

#define GLOAD_LDS16(g, l) __builtin_amdgcn_global_load_lds(                    \
    (const __attribute__((address_space(1))) void*)(g),                        \
    (__attribute__((address_space(3))) void*)(l), 16, 0, 0)

// ---------------- kernel 0: fp32 -> bf16 (plain + log2-prescaled) ----------------
__global__ void jl_cvt(const float* __restrict__ in, __bf16* __restrict__ b_out,
                       __bf16* __restrict__ a_out) {
    int i = (blockIdx.x * 256 + threadIdx.x) * 8;
    float4 a = *(const float4*)(in + i);
    float4 b = *(const float4*)(in + i + 4);
    bf16x8 v, w;
    v[0] = (__bf16)a.x; v[1] = (__bf16)a.y; v[2] = (__bf16)a.z; v[3] = (__bf16)a.w;
    v[4] = (__bf16)b.x; v[5] = (__bf16)b.y; v[6] = (__bf16)b.z; v[7] = (__bf16)b.w;
    w[0] = (__bf16)(a.x * CSCALE); w[1] = (__bf16)(a.y * CSCALE);
    w[2] = (__bf16)(a.z * CSCALE); w[3] = (__bf16)(a.w * CSCALE);
    w[4] = (__bf16)(b.x * CSCALE); w[5] = (__bf16)(b.y * CSCALE);
    w[6] = (__bf16)(b.z * CSCALE); w[7] = (__bf16)(b.w * CSCALE);
    *(bf16x8*)(b_out + i) = v;
    *(bf16x8*)(a_out + i) = w;
}

// ---------------- kernel 1: fused GEMM + online log2-sum-exp2 partials ----------------
// grid = (NROWS/BM) * NSPLIT blocks, 256 threads (4 waves).
// block: rows [rbk*64, +64), cols [q*256, +256). wave w: rows [rbk*64 + 16w, +16)
__global__ __launch_bounds__(256, 2) void jl_main(const __bf16* __restrict__ ab,
                                                  const __bf16* __restrict__ bb,
                                                  float* __restrict__ pm,
                                                  float* __restrict__ ps,
                                                  float* __restrict__ pos) {
    __shared__ bf16x8 smem[2][16][64];   // fragment-ordered B tile, double buffered

    const int rbk  = blockIdx.x >> 4;
    const int q    = blockIdx.x & 15;
    const int wave = threadIdx.x >> 6;
    const int lane = threadIdx.x & 63;

    const int row0 = rbk * BM + wave * 16;
    const int col0 = q * QCOLS;
    const int lrow = lane & 15;   // A row / B col / D col
    const int lk   = lane >> 4;   // k sub-block 0..3

    // A fragments (log2-prescaled), pinned resident: 16 x 4 VGPR = 64 VGPR.
    bf16x8 afrag[16];
    {
        const __bf16* arow = ab + (size_t)(row0 + lrow) * DDIM + lk * 8;
        #pragma unroll
        for (int kb = 0; kb < 16; ++kb)
            afrag[kb] = *(const bf16x8*)(arow + kb * 32);
    }
    #pragma unroll
    for (int kb = 0; kb < 16; ++kb) asm volatile("" : "+v"(afrag[kb]));

    // per-lane fragment-ordered global source for B staging
    const __bf16* gB = bb + (size_t)(col0 + lrow) * DDIM + lk * 8;

    // prologue: stage tile 0 into buf 0 (wave w stages kb = 4w..4w+3)
    #pragma unroll
    for (int i = 0; i < 4; ++i)
        GLOAD_LDS16(gB + (wave * 4 + i) * 32, &smem[0][wave * 4 + i][0]);
    __syncthreads();

    float m[4], s[4];
    #pragma unroll
    for (int r = 0; r < 4; ++r) { m[r] = NEG_BIG; s[r] = 0.0f; }

    int cur = 0;
    for (int jt = 0; jt < NT; ++jt) {
        if (jt + 1 < NT) {
            const __bf16* gN = gB + (size_t)(jt + 1) * 16 * DDIM;
            #pragma unroll
            for (int i = 0; i < 4; ++i)
                GLOAD_LDS16(gN + (wave * 4 + i) * 32, &smem[cur ^ 1][wave * 4 + i][0]);
        }

        // 2 independent MFMA chains of depth 8
        f32x4 acc[2];
        acc[0] = (f32x4){0.f, 0.f, 0.f, 0.f};
        acc[1] = (f32x4){0.f, 0.f, 0.f, 0.f};
        #pragma unroll
        for (int kb = 0; kb < 16; ++kb) {
            bf16x8 b = smem[cur][kb][lane];
            acc[kb & 1] = __builtin_amdgcn_mfma_f32_16x16x32_bf16(afrag[kb], b, acc[kb & 1], 0, 0, 0);
        }
        f32x4 y4 = acc[0] + acc[1];   // y = sim * 10 * log2(e)  (log2 units)

        const int ctile = col0 + jt * 16;   // wave-uniform

        if (ctile == (row0 ^ 2048)) {       // positive-pair tile (1 tile per wave total)
            #pragma unroll
            for (int r = 0; r < 4; ++r)
                if (lrow == 4 * lk + r) pos[row0 + 4 * lk + r] = y4[r];
        }

        if (ctile == row0) {
            // diagonal tile (at most 1 per wave): masked online update
            #pragma unroll
            for (int r = 0; r < 4; ++r) {
                const bool isd = (lrow == 4 * lk + r);
                float y  = isd ? NEG_BIG : y4[r];
                float mn = fmaxf(m[r], y);
                float e  = isd ? 0.0f : __builtin_amdgcn_exp2f(y - mn);
                s[r] = s[r] * __builtin_amdgcn_exp2f(m[r] - mn) + e;
                m[r] = mn;
            }
        } else {
            // generic tile: defer-max fast path
            float t0 = y4[0] - m[0], t1 = y4[1] - m[1];
            float t2 = y4[2] - m[2], t3 = y4[3] - m[3];
            float dmax = fmaxf(fmaxf(t0, t1), fmaxf(t2, t3));
            if (__any(dmax > THR)) {
                #pragma unroll
                for (int r = 0; r < 4; ++r) {
                    float mn = fmaxf(m[r], y4[r]);
                    s[r] = s[r] * __builtin_amdgcn_exp2f(m[r] - mn)
                         + __builtin_amdgcn_exp2f(y4[r] - mn);
                    m[r] = mn;
                }
            } else {
                s[0] += __builtin_amdgcn_exp2f(t0);
                s[1] += __builtin_amdgcn_exp2f(t1);
                s[2] += __builtin_amdgcn_exp2f(t2);
                s[3] += __builtin_amdgcn_exp2f(t3);
            }
        }

        __syncthreads();   // all waves done reading cur; staged loads drained
        cur ^= 1;
    }

    // merge (m,s) across the 16 lanes of each row group, write partials
    #pragma unroll
    for (int r = 0; r < 4; ++r) {
        float mm = m[r], ss = s[r];
        #pragma unroll
        for (int off = 1; off < 16; off <<= 1) {
            float mo = __shfl_xor(mm, off, 64);
            float so = __shfl_xor(ss, off, 64);
            float mn = fmaxf(mm, mo);
            ss = ss * __builtin_amdgcn_exp2f(mm - mn) + so * __builtin_amdgcn_exp2f(mo - mn);
            mm = mn;
        }
        if (lrow == 0) {
            const int grow = row0 + 4 * lk + r;
            pm[grow * NSPLIT + q] = mm;
            ps[grow * NSPLIT + q] = ss;
        }
    }
}

// ---------------- kernel 2: merge partials -> scalar loss ----------------
__global__ void jl_merge(const float* __restrict__ pm, const float* __restrict__ ps,
                         const float* __restrict__ pos, float* __restrict__ out) {
    __shared__ float red[256];
    const int t = threadIdx.x;
    float acc = 0.0f;
    for (int i = t; i < NROWS; i += 256) {
        float mb = NEG_BIG;
        #pragma unroll
        for (int qq = 0; qq < NSPLIT; ++qq) mb = fmaxf(mb, pm[i * NSPLIT + qq]);
        float st = 0.0f;
        #pragma unroll
        for (int qq = 0; qq < NSPLIT; ++qq)
            st += ps[i * NSPLIT + qq] * __builtin_amdgcn_exp2f(pm[i * NSPLIT + qq] - mb);
        // loss_i (nat units) = ln2 * (mb + log2(st) - pos_i)
        acc += mb + __builtin_amdgcn_logf(st) - pos[i];
    }
    red[t] = acc;
    __syncthreads();
    for (int off = 128; off > 0; off >>= 1) {
        if (t < off) red[t] += red[t + off];
        __syncthreads();
    }
    if (t == 0) out[0] = red[0] * (LN2 / (float)NROWS);
}

extern "C" void kernel_launch(void* const* d_in, const int* in_sizes, int n_in,
                              void* d_out, int out_size, void* d_ws, size_t ws_size,
                              hipStream_t stream) {
    const float* rep = (const float*)d_in[0];
    float* out = (float*)d_out;

    // workspace layout: bbuf 4MB | abuf 4MB | pm | ps | pos
    __bf16* bbuf = (__bf16*)d_ws;
    __bf16* abuf = bbuf + (size_t)NROWS * DDIM;
    float*  pm   = (float*)(abuf + (size_t)NROWS * DDIM);
    float*  ps   = pm + NROWS * NSPLIT;
    float*  pos  = ps + NROWS * NSPLIT;

    jl_cvt<<<(NROWS * DDIM) / (256 * 8), 256, 0, stream>>>(rep, bbuf, abuf);
    jl_main<<<(NROWS / BM) * NSPLIT, 256, 0, stream>>>(abuf, bbuf, pm, ps, pos);
    jl_merge<<<1, 256, 0, stream>>>(pm, ps, pos, out);
}

// Round 4
// 52.779 us; speedup vs baseline: 2.6371x; 1.1809x over previous
//
#include <hip/hip_runtime.h>
#include <hip/hip_bf16.h>

// SimCLR NT-Xent loss v4: M=32 rows/wave (2 MFMAs per B-fragment, halves LDS
// traffic), 4-buffer LDS ring with counted-vmcnt prefetch (depth 2, raw
// s_barrier, never vmcnt(0) in steady state), log2-unit defer-max epilogue.

#define NROWS 4096
#define DDIM  512
#define NSPLIT 16                // column splits
#define QCOLS (NROWS / NSPLIT)   // 256 cols per split
#define NT (QCOLS / 16)          // 16 column tiles per block
#define BM 128                   // rows per block (4 waves x 32)
#define NEG_BIG (-3.0e38f)
#define CSCALE 14.4269504088896340736f   // 10 * log2(e): logits in log2 units
#define LN2 0.69314718055994530942f
#define THR 40.0f                // defer-max threshold (log2 units)

typedef __bf16 bf16x8 __attribute__((ext_vector_type(8)));
typedef float  f32x4  __attribute__((ext_vector_type(4)));

#define GLOAD_LDS16(g, l) __builtin_amdgcn_global_load_lds(                    \
    (const __attribute__((address_space(1))) void*)(g),                        \
    (__attribute__((address_space(3))) void*)(l), 16, 0, 0)

// ---------------- kernel 0: fp32 -> bf16 (plain + log2-prescaled) ----------------
__global__ void jl_cvt(const float* __restrict__ in, __bf16* __restrict__ b_out,
                       __bf16* __restrict__ a_out) {
    int i = (blockIdx.x * 256 + threadIdx.x) * 8;
    float4 a = *(const float4*)(in + i);
    float4 b = *(const float4*)(in + i + 4);
    bf16x8 v, w;
    v[0] = (__bf16)a.x; v[1] = (__bf16)a.y; v[2] = (__bf16)a.z; v[3] = (__bf16)a.w;
    v[4] = (__bf16)b.x; v[5] = (__bf16)b.y; v[6] = (__bf16)b.z; v[7] = (__bf16)b.w;
    w[0] = (__bf16)(a.x * CSCALE); w[1] = (__bf16)(a.y * CSCALE);
    w[2] = (__bf16)(a.z * CSCALE); w[3] = (__bf16)(a.w * CSCALE);
    w[4] = (__bf16)(b.x * CSCALE); w[5] = (__bf16)(b.y * CSCALE);
    w[6] = (__bf16)(b.z * CSCALE); w[7] = (__bf16)(b.w * CSCALE);
    *(bf16x8*)(b_out + i) = v;
    *(bf16x8*)(a_out + i) = w;
}

// ---------------- kernel 1: fused GEMM + online log2-sum-exp2 partials ----------------
// grid = (NROWS/BM) * NSPLIT = 32*16 = 512 blocks, 256 threads (4 waves).
// block: rows [rbk*128, +128), cols [q*256, +256). wave w: rows [.. + 32w, +32)
__global__ __launch_bounds__(256, 2) void jl_main(const __bf16* __restrict__ ab,
                                                  const __bf16* __restrict__ bb,
                                                  float* __restrict__ pm,
                                                  float* __restrict__ ps,
                                                  float* __restrict__ pos) {
    __shared__ bf16x8 smem[4][16][64];   // 4-buffer ring, fragment-ordered, 64 KB

    const int rbk  = blockIdx.x >> 4;   // 0..31
    const int q    = blockIdx.x & 15;
    const int wave = threadIdx.x >> 6;
    const int lane = threadIdx.x & 63;

    const int row0 = rbk * BM + wave * 32;   // wave's first row (32 rows)
    const int col0 = q * QCOLS;
    const int lrow = lane & 15;
    const int lk   = lane >> 4;

    // A fragments (log2-prescaled), two 16-row halves: 32 x bf16x8 = 128 VGPR
    bf16x8 afA[16], afB[16];
    {
        const __bf16* arow = ab + (size_t)(row0 + lrow) * DDIM + lk * 8;
        #pragma unroll
        for (int kb = 0; kb < 16; ++kb) {
            afA[kb] = *(const bf16x8*)(arow + kb * 32);
            afB[kb] = *(const bf16x8*)(arow + 16 * DDIM + kb * 32);
        }
    }
    #pragma unroll
    for (int kb = 0; kb < 16; ++kb) {
        asm volatile("" : "+v"(afA[kb]));
        asm volatile("" : "+v"(afB[kb]));
    }
    asm volatile("" ::: "memory");   // A-loads drained before staging begins

    // per-lane fragment-ordered global source for B staging
    const __bf16* gB = bb + (size_t)(col0 + lrow) * DDIM + lk * 8;

#define STAGE(T)                                                               \
    do {                                                                       \
        const __bf16* g_ = gB + (size_t)(T) * 16 * DDIM;                       \
        _Pragma("unroll")                                                      \
        for (int i_ = 0; i_ < 4; ++i_) {                                       \
            int kb_ = wave * 4 + i_;                                           \
            GLOAD_LDS16(g_ + kb_ * 32, &smem[(T) & 3][kb_][0]);                \
        }                                                                      \
    } while (0)

    STAGE(0);
    STAGE(1);

    float m[2][4], s[2][4];
    #pragma unroll
    for (int h = 0; h < 2; ++h)
        #pragma unroll
        for (int r = 0; r < 4; ++r) { m[h][r] = NEG_BIG; s[h][r] = 0.0f; }

    for (int jt = 0; jt < NT; ++jt) {
        if (jt + 2 < NT) STAGE(jt + 2);

        // counted vmcnt: keep 2 tiles in flight, drain only at the tail
        if (jt < NT - 2)       asm volatile("s_waitcnt vmcnt(8)" ::: "memory");
        else if (jt == NT - 2) asm volatile("s_waitcnt vmcnt(4)" ::: "memory");
        else                   asm volatile("s_waitcnt vmcnt(0)" ::: "memory");
        __builtin_amdgcn_s_barrier();
        __builtin_amdgcn_sched_barrier(0);

        const int cb = jt & 3;
        f32x4 accA0 = {0.f,0.f,0.f,0.f}, accA1 = {0.f,0.f,0.f,0.f};
        f32x4 accB0 = {0.f,0.f,0.f,0.f}, accB1 = {0.f,0.f,0.f,0.f};
        #pragma unroll
        for (int kb = 0; kb < 16; ++kb) {
            bf16x8 bf = smem[cb][kb][lane];
            if (kb & 1) {
                accA1 = __builtin_amdgcn_mfma_f32_16x16x32_bf16(afA[kb], bf, accA1, 0, 0, 0);
                accB1 = __builtin_amdgcn_mfma_f32_16x16x32_bf16(afB[kb], bf, accB1, 0, 0, 0);
            } else {
                accA0 = __builtin_amdgcn_mfma_f32_16x16x32_bf16(afA[kb], bf, accA0, 0, 0, 0);
                accB0 = __builtin_amdgcn_mfma_f32_16x16x32_bf16(afB[kb], bf, accB0, 0, 0, 0);
            }
        }
        f32x4 y[2];
        y[0] = accA0 + accA1;   // rows row0    + 4*lk + r, col col0+jt*16+lrow
        y[1] = accB0 + accB1;   // rows row0+16 + 4*lk + r

        const int ctile = col0 + jt * 16;   // wave-uniform

        // positive-pair tiles (uniform, rare): partner of row i is i^2048
        if (ctile == (row0 ^ 2048)) {
            #pragma unroll
            for (int r = 0; r < 4; ++r)
                if (lrow == 4 * lk + r) pos[row0 + 4 * lk + r] = y[0][r];
        }
        if (ctile == ((row0 + 16) ^ 2048)) {
            #pragma unroll
            for (int r = 0; r < 4; ++r)
                if (lrow == 4 * lk + r) pos[row0 + 16 + 4 * lk + r] = y[1][r];
        }

        const bool d0 = (ctile == row0), d1 = (ctile == row0 + 16);
        if (d0 || d1) {
            // diagonal tile (rare): masked full online update
            #pragma unroll
            for (int h = 0; h < 2; ++h) {
                const bool dh = h ? d1 : d0;
                #pragma unroll
                for (int r = 0; r < 4; ++r) {
                    const bool isd = dh && (lrow == 4 * lk + r);
                    float yv = isd ? NEG_BIG : y[h][r];
                    float mn = fmaxf(m[h][r], yv);
                    float e  = isd ? 0.0f : __builtin_amdgcn_exp2f(yv - mn);
                    s[h][r] = s[h][r] * __builtin_amdgcn_exp2f(m[h][r] - mn) + e;
                    m[h][r] = mn;
                }
            }
        } else {
            float t0 = y[0][0] - m[0][0], t1 = y[0][1] - m[0][1];
            float t2 = y[0][2] - m[0][2], t3 = y[0][3] - m[0][3];
            float t4 = y[1][0] - m[1][0], t5 = y[1][1] - m[1][1];
            float t6 = y[1][2] - m[1][2], t7 = y[1][3] - m[1][3];
            float dmax = fmaxf(fmaxf(fmaxf(t0, t1), fmaxf(t2, t3)),
                               fmaxf(fmaxf(t4, t5), fmaxf(t6, t7)));
            if (__any(dmax > THR)) {
                #pragma unroll
                for (int h = 0; h < 2; ++h)
                    #pragma unroll
                    for (int r = 0; r < 4; ++r) {
                        float mn = fmaxf(m[h][r], y[h][r]);
                        s[h][r] = s[h][r] * __builtin_amdgcn_exp2f(m[h][r] - mn)
                                + __builtin_amdgcn_exp2f(y[h][r] - mn);
                        m[h][r] = mn;
                    }
            } else {
                s[0][0] += __builtin_amdgcn_exp2f(t0);
                s[0][1] += __builtin_amdgcn_exp2f(t1);
                s[0][2] += __builtin_amdgcn_exp2f(t2);
                s[0][3] += __builtin_amdgcn_exp2f(t3);
                s[1][0] += __builtin_amdgcn_exp2f(t4);
                s[1][1] += __builtin_amdgcn_exp2f(t5);
                s[1][2] += __builtin_amdgcn_exp2f(t6);
                s[1][3] += __builtin_amdgcn_exp2f(t7);
            }
        }
    }
#undef STAGE

    // merge (m,s) across the 16 lanes of each row group, write partials
    #pragma unroll
    for (int h = 0; h < 2; ++h)
        #pragma unroll
        for (int r = 0; r < 4; ++r) {
            float mm = m[h][r], ss = s[h][r];
            #pragma unroll
            for (int off = 1; off < 16; off <<= 1) {
                float mo = __shfl_xor(mm, off, 64);
                float so = __shfl_xor(ss, off, 64);
                float mn = fmaxf(mm, mo);
                ss = ss * __builtin_amdgcn_exp2f(mm - mn)
                   + so * __builtin_amdgcn_exp2f(mo - mn);
                mm = mn;
            }
            if (lrow == 0) {
                const int grow = row0 + 16 * h + 4 * lk + r;
                pm[grow * NSPLIT + q] = mm;
                ps[grow * NSPLIT + q] = ss;
            }
        }
}

// ---------------- kernel 2: merge partials -> scalar loss ----------------
__global__ void jl_merge(const float* __restrict__ pm, const float* __restrict__ ps,
                         const float* __restrict__ pos, float* __restrict__ out) {
    __shared__ float red[256];
    const int t = threadIdx.x;
    float acc = 0.0f;
    for (int i = t; i < NROWS; i += 256) {
        float mb = NEG_BIG;
        #pragma unroll
        for (int qq = 0; qq < NSPLIT; ++qq) mb = fmaxf(mb, pm[i * NSPLIT + qq]);
        float st = 0.0f;
        #pragma unroll
        for (int qq = 0; qq < NSPLIT; ++qq)
            st += ps[i * NSPLIT + qq] * __builtin_amdgcn_exp2f(pm[i * NSPLIT + qq] - mb);
        // loss_i (nat units) = ln2 * (mb + log2(st) - pos_i)
        acc += mb + __builtin_amdgcn_logf(st) - pos[i];
    }
    red[t] = acc;
    __syncthreads();
    for (int off = 128; off > 0; off >>= 1) {
        if (t < off) red[t] += red[t + off];
        __syncthreads();
    }
    if (t == 0) out[0] = red[0] * (LN2 / (float)NROWS);
}

extern "C" void kernel_launch(void* const* d_in, const int* in_sizes, int n_in,
                              void* d_out, int out_size, void* d_ws, size_t ws_size,
                              hipStream_t stream) {
    const float* rep = (const float*)d_in[0];
    float* out = (float*)d_out;

    // workspace layout: bbuf 4MB | abuf 4MB | pm | ps | pos
    __bf16* bbuf = (__bf16*)d_ws;
    __bf16* abuf = bbuf + (size_t)NROWS * DDIM;
    float*  pm   = (float*)(abuf + (size_t)NROWS * DDIM);
    float*  ps   = pm + NROWS * NSPLIT;
    float*  pos  = ps + NROWS * NSPLIT;

    jl_cvt<<<(NROWS * DDIM) / (256 * 8), 256, 0, stream>>>(rep, bbuf, abuf);
    jl_main<<<(NROWS / BM) * NSPLIT, 256, 0, stream>>>(abuf, bbuf, pm, ps, pos);
    jl_merge<<<1, 256, 0, stream>>>(pm, ps, pos, out);
}